// Round 4
// baseline (256.866 us; speedup 1.0000x reference)
//
#include <hip/hip_runtime.h>

// DynamicUpsamplingFilter: out[b,c,h,w] = sum_{dy,dx} f[b,3*dy+dx,h,w] * x[b,c,h+dy-1,w+dx-1]
// x: [4,128,180,320] f32, filters: [4,9,180,320] f32, out: [4,128,180,320] f32.
//
// R7: software-pipelined channel loop. R3-R6 all ran 90-110us with every
// pipe idle: waves had loads in flight <5% of their lifetime (Little's law:
// 2 TB/s = ~2KB/CU in flight at ~600cy latency). Fix is structural, not
// occupancy: per-thread channel loop with 2-deep register double-buffer --
// stage(k+1)'s 9 loads issue BEFORE compute(k)'s FMAs, so every wave keeps
// a ~4.6KB clause in flight continuously.
//   - thread = (b, h, w4, cq); 8 channels per thread, single output row.
//   - 9 filter float4s in regs (36 VGPR, not R3's 72); ALL boundary
//     handling folded into the taps once pre-loop (zero the components
//     that would multiply padding; x loads use clamped addresses whose
//     values are killed by the zeroed taps). Inner loop branch-free:
//     9 loads + 36 FMA + 1 store.
//   - No LDS, no barriers. 3600 blocks; bijective XCD swizzle gives each
//     XCD a contiguous (b,h)-band so halo rows stay L2-local.

#define CC 128
#define HH 180
#define WW 320
#define W4 80
#define NF 9
#define CPT 8                   // channels per thread
#define CQ  (CC / CPT)          // 16
#define CST (HH * WW)           // channel stride (floats)
#define NTHR (4 * HH * CQ * W4) // 921600
#define NBLK (NTHR / 256)       // 3600
#define XCHUNK (NBLK / 8)       // 450

__global__ __launch_bounds__(256, 4) void duf_kernel(
    const float* __restrict__ x,
    const float* __restrict__ f,
    float* __restrict__ out)
{
    // XCD-aware bijective swizzle (3600 % 8 == 0)
    int raw = blockIdx.x;
    int wg  = (raw & 7) * XCHUNK + (raw >> 3);
    int n   = wg * 256 + threadIdx.x;

    int w4 = n % W4;            // lanes consecutive in w4 -> coalesced
    int t  = n / W4;
    int cq = t % CQ;
    t /= CQ;
    int h  = t % HH;
    int b  = t / HH;

    const float4* f4 = (const float4*)f;
    float4* o4 = (float4*)out;
    const float4 z4 = make_float4(0.f, 0.f, 0.f, 0.f);

    // ---- 9 taps in registers; boundary handling folded into taps.
    float4 fw[NF];
    size_t fb = ((size_t)(b * NF) * HH + h) * W4 + w4;
#pragma unroll
    for (int i = 0; i < NF; ++i) fw[i] = f4[fb + (size_t)i * (HH * W4)];
    if (h == 0)      { fw[0] = z4; fw[1] = z4; fw[2] = z4; }      // x row h-1 is pad
    if (h == HH - 1) { fw[6] = z4; fw[7] = z4; fw[8] = z4; }      // x row h+1 is pad
    if (w4 == 0)     { fw[0].x = 0.f; fw[3].x = 0.f; fw[6].x = 0.f; } // x[-1] is pad
    if (w4 == W4-1)  { fw[2].w = 0.f; fw[5].w = 0.f; fw[8].w = 0.f; } // x[320] is pad

    // ---- loop-invariant x offsets (32-bit float indices; x has 29.5M floats)
    const int wB = w4 * 4;
    const int wA = (w4 == 0)      ? wB     : wB - 1;   // clamped; tap zeroed
    const int wC = (w4 == W4 - 1) ? wB + 3 : wB + 4;   // clamped; tap zeroed
    const int r0 = (h == 0)       ? 0      : h - 1;    // clamped; taps zeroed
    const int r2 = (h == HH - 1)  ? HH - 1 : h + 1;    // clamped; taps zeroed
    unsigned orow[3] = { (unsigned)(r0 * WW), (unsigned)(h * WW), (unsigned)(r2 * WW) };
    const unsigned cbase = (unsigned)(b * CC + cq * CPT) * (unsigned)CST;

    // ---- software-pipelined channel loop (fully unrolled, static indexing)
    float4 Bv[2][3]; float aLv[2][3], cRv[2][3];

#pragma unroll
    for (int r = 0; r < 3; ++r) {                      // prologue: stage k=0
        const float* p = x + (size_t)(cbase + orow[r]);
        Bv[0][r]  = *(const float4*)(p + wB);
        aLv[0][r] = p[wA];
        cRv[0][r] = p[wC];
    }

    size_t ob = ((size_t)(b * CC + cq * CPT) * HH + h) * W4 + w4;

#pragma unroll
    for (int k = 0; k < CPT; ++k) {
        const int cur = k & 1, nxt = cur ^ 1;
        if (k + 1 < CPT) {                             // issue stage k+1 first
            const unsigned cb = cbase + (unsigned)((k + 1) * CST);
#pragma unroll
            for (int r = 0; r < 3; ++r) {
                const float* p = x + (size_t)(cb + orow[r]);
                Bv[nxt][r]  = *(const float4*)(p + wB);
                aLv[nxt][r] = p[wA];
                cRv[nxt][r] = p[wC];
            }
        }
        float4 acc = z4;                               // compute k
#pragma unroll
        for (int r = 0; r < 3; ++r) {
            const float4 f0 = fw[3*r], f1 = fw[3*r+1], f2 = fw[3*r+2];
            const float4 B = Bv[cur][r];
            const float aL = aLv[cur][r], cR = cRv[cur][r];
            acc.x = fmaf(f0.x, aL,  fmaf(f1.x, B.x, fmaf(f2.x, B.y, acc.x)));
            acc.y = fmaf(f0.y, B.x, fmaf(f1.y, B.y, fmaf(f2.y, B.z, acc.y)));
            acc.z = fmaf(f0.z, B.y, fmaf(f1.z, B.z, fmaf(f2.z, B.w, acc.z)));
            acc.w = fmaf(f0.w, B.z, fmaf(f1.w, B.w, fmaf(f2.w, cR,  acc.w)));
        }
        o4[ob + (size_t)k * (HH * W4)] = acc;
    }
}

extern "C" void kernel_launch(void* const* d_in, const int* in_sizes, int n_in,
                              void* d_out, int out_size, void* d_ws, size_t ws_size,
                              hipStream_t stream) {
    const float* x = (const float*)d_in[0];
    const float* f = (const float*)d_in[1];
    float* out = (float*)d_out;
    duf_kernel<<<NBLK, 256, 0, stream>>>(x, f, out);
}

// Round 5
// 228.016 us; speedup vs baseline: 1.1265x; 1.1265x over previous
//
#include <hip/hip_runtime.h>

// DynamicUpsamplingFilter: out[b,c,h,w] = sum_{dy,dx} f[b,3*dy+dx,h,w] * x[b,c,h+dy-1,w+dx-1]
// x: [4,128,180,320] f32, filters: [4,9,180,320] f32, out: [4,128,180,320] f32.
//
// R8: long-lived streaming waves. R3-R7 post-mortems: every structure either
// (a) fully unrolled its channel loop -> compiler re-sank the 9 filter-tap
// loads into each iteration (R7 compiled at 36 VGPR despite fw[9] in source
// = taps reloaded 8x, loads serialized on tiny reg windows), or (b) was a
// one-shot wave (R5/R6) paying address-chain + full latency + wave turnover
// 57K times. This kernel:
//   - DYNAMIC channel-loop bound (kernarg): cannot fully unroll, so LICM
//     hoists the 9 taps into registers and they stay there (36 VGPR held).
//   - Per iteration only 3 coalesced float4 row loads; left/right halo via
//     __shfl_up/down of neighbor lanes' registers (R6's 6 scalar gathers
//     cost ~100 extra L1 lines/iter). Wave-edge lanes fixed by one 2-lane
//     masked load per row. All boundary zeroing folded into the taps.
//   - No LDS, no barriers, no unroll pragma. 1800 blocks x 256.

#define CC 128
#define HH 180
#define WW 320
#define W4 80
#define PL (HH * W4)          // 14400 f4 per channel plane
#define CSPLIT 8              // channel groups per plane position
#define CPG (CC / CSPLIT)     // 16 channels per thread
#define NBLK (4 * PL / 256 * CSPLIT)  // 225 * 8 = 1800

__global__ __launch_bounds__(256, 4) void duf_kernel(
    const float* __restrict__ x,
    const float* __restrict__ f,
    float* __restrict__ out,
    int nch)                  // = CPG, runtime-opaque to block full unroll
{
    int raw = blockIdx.x;
    int pb  = raw >> 3;                   // plane-block 0..224
    int cs  = raw & 7;                    // channel group 0..7
    int gp  = pb * 256 + threadIdx.x;     // global plane-f4 id, 0..57599
    int b   = gp / PL;
    int p   = gp - b * PL;                // f4 index within plane
    int h   = p / W4;
    int w4  = p - h * W4;
    int lane = threadIdx.x & 63;

    const float4* f4p = (const float4*)f;
    const float4 z4 = make_float4(0.f, 0.f, 0.f, 0.f);

    // ---- 9 taps in registers, boundary handling folded in
    float4 fw[9];
    size_t fb = (size_t)(b * 9) * PL + p;
#pragma unroll
    for (int i = 0; i < 9; ++i) fw[i] = f4p[fb + (size_t)i * PL];
    if (h == 0)      { fw[0] = z4; fw[1] = z4; fw[2] = z4; }
    if (h == HH - 1) { fw[6] = z4; fw[7] = z4; fw[8] = z4; }
    if (w4 == 0)     { fw[0].x = 0.f; fw[3].x = 0.f; fw[6].x = 0.f; }
    if (w4 == W4-1)  { fw[2].w = 0.f; fw[5].w = 0.f; fw[8].w = 0.f; }

    // ---- loop-invariant addressing (f4 units within one channel plane)
    const int pr0 = (h == 0)      ? p : p - W4;   // clamped; taps zeroed
    const int pr2 = (h == HH - 1) ? p : p + W4;
    const bool e0  = (lane == 0);
    const bool e63 = (lane == 63);
    const int  eo  = e0 ? -1 : 4;                 // edge scalar offset

    const size_t cbase = (size_t)(b * CC + cs * CPG) * PL;  // f4 units
    const float4* xc4 = (const float4*)x + cbase;
    float4*       oc4 = (float4*)out + cbase;

    for (int k = 0; k < nch; ++k) {
        const float4* xp = xc4 + (size_t)k * PL;
        // 3 coalesced row loads
        float4 B0 = xp[pr0];
        float4 B1 = xp[p];
        float4 B2 = xp[pr2];
        // wave-edge scalars (lanes 0 and 63 only): lane0 -> col-1, lane63 -> col+4
        float g0 = 0.f, g1 = 0.f, g2 = 0.f;
        if (e0 | e63) {
            const float* xs = (const float*)xp;
            g0 = xs[max(4 * pr0 + eo, 0)];
            g1 = xs[max(4 * p   + eo, 0)];
            g2 = xs[min(4 * pr2 + eo, 4 * PL - 1)];
        }
        // halo columns from neighbor lanes
        float aL0 = __shfl_up(B0.w, 1);  if (e0) aL0 = g0;
        float aL1 = __shfl_up(B1.w, 1);  if (e0) aL1 = g1;
        float aL2 = __shfl_up(B2.w, 1);  if (e0) aL2 = g2;
        float cR0 = __shfl_down(B0.x, 1); if (e63) cR0 = g0;
        float cR1 = __shfl_down(B1.x, 1); if (e63) cR1 = g1;
        float cR2 = __shfl_down(B2.x, 1); if (e63) cR2 = g2;

        float4 acc = z4;
        // row h-1 (taps 0..2)
        acc.x = fmaf(fw[0].x, aL0,  fmaf(fw[1].x, B0.x, fmaf(fw[2].x, B0.y, acc.x)));
        acc.y = fmaf(fw[0].y, B0.x, fmaf(fw[1].y, B0.y, fmaf(fw[2].y, B0.z, acc.y)));
        acc.z = fmaf(fw[0].z, B0.y, fmaf(fw[1].z, B0.z, fmaf(fw[2].z, B0.w, acc.z)));
        acc.w = fmaf(fw[0].w, B0.z, fmaf(fw[1].w, B0.w, fmaf(fw[2].w, cR0,  acc.w)));
        // row h (taps 3..5)
        acc.x = fmaf(fw[3].x, aL1,  fmaf(fw[4].x, B1.x, fmaf(fw[5].x, B1.y, acc.x)));
        acc.y = fmaf(fw[3].y, B1.x, fmaf(fw[4].y, B1.y, fmaf(fw[5].y, B1.z, acc.y)));
        acc.z = fmaf(fw[3].z, B1.y, fmaf(fw[4].z, B1.z, fmaf(fw[5].z, B1.w, acc.z)));
        acc.w = fmaf(fw[3].w, B1.z, fmaf(fw[4].w, B1.w, fmaf(fw[5].w, cR1,  acc.w)));
        // row h+1 (taps 6..8)
        acc.x = fmaf(fw[6].x, aL2,  fmaf(fw[7].x, B2.x, fmaf(fw[8].x, B2.y, acc.x)));
        acc.y = fmaf(fw[6].y, B2.x, fmaf(fw[7].y, B2.y, fmaf(fw[8].y, B2.z, acc.y)));
        acc.z = fmaf(fw[6].z, B2.y, fmaf(fw[7].z, B2.z, fmaf(fw[8].z, B2.w, acc.z)));
        acc.w = fmaf(fw[6].w, B2.z, fmaf(fw[7].w, B2.w, fmaf(fw[8].w, cR2,  acc.w)));

        oc4[(size_t)k * PL + p] = acc;
    }
}

extern "C" void kernel_launch(void* const* d_in, const int* in_sizes, int n_in,
                              void* d_out, int out_size, void* d_ws, size_t ws_size,
                              hipStream_t stream) {
    const float* x = (const float*)d_in[0];
    const float* f = (const float*)d_in[1];
    float* out = (float*)d_out;
    duf_kernel<<<NBLK, 256, 0, stream>>>(x, f, out, CPG);
}